// Round 3
// baseline (554.792 us; speedup 1.0000x reference)
//
#include <hip/hip_runtime.h>

#define NLEV 8
#define COLS 43   // 8*(2+3)+3
#define TPB1 256  // K1 gather kernel
#define TPB  64   // K2 assemble / fallback kernel

typedef float v4f __attribute__((ext_vector_type(4)));
typedef float v2f __attribute__((ext_vector_type(2)));

// per-level cumulative start offsets and pow2 size masks
// sizes: 4096, 32768, 262144, 524288 x5  (all pow2 -> mod == and)
__device__ __constant__ unsigned off_c[NLEV]  = {0u, 4096u, 36864u, 299008u,
                                                 823296u, 1347584u, 1871872u, 2396160u};
__device__ __constant__ unsigned mask_c[NLEV] = {4095u, 32767u, 262143u, 524287u,
                                                 524287u, 524287u, 524287u, 524287u};

// ---------------- K1: level-partitioned gather ----------------
// level = blockIdx & 7 -> blocks of one level land on one XCD (dispatch
// round-robins XCDs), so that level's table (<=4MB) stays resident in that
// XCD's 4MB L2 -> gathers become L2 hits instead of 641MB of fabric fills.
// Inputs are nt-loaded and feats nt-stored so streams don't evict the table.
__global__ __launch_bounds__(TPB1) void gather_kernel(
    const float* __restrict__ inputs,   // [N,3]
    const float2* __restrict__ emb,     // [2920448,2]
    v2f* __restrict__ ws,               // [8][N] feats
    int N)
{
    const int level = blockIdx.x & 7;           // wave-uniform -> scalar regs
    const int i = (blockIdx.x >> 3) * TPB1 + threadIdx.x;
    if (i >= N) return;

    const float x0 = __builtin_nontemporal_load(&inputs[3 * i + 0]);
    const float x1 = __builtin_nontemporal_load(&inputs[3 * i + 1]);
    const float x2 = __builtin_nontemporal_load(&inputs[3 * i + 2]);

    const float res = (float)(16 << level);
    const float a = x0 * res, b = x1 * res, c = x2 * res;
    const float fa = floorf(a), fb = floorf(b), fc = floorf(c);
    const float ga = a - fa, gb = b - fb, gc = c - fc;
    const unsigned na = (unsigned)fa + (ga < 0.5f ? 0u : 1u);
    const unsigned nb = (unsigned)fb + (gb < 0.5f ? 0u : 1u);
    const unsigned nc = (unsigned)fc + (gc < 0.5f ? 0u : 1u);
    const unsigned h = na ^ (nb * 2654435761u) ^ (nc * 805459861u);
    const unsigned id = (h & mask_c[level]) + off_c[level];

    const float2 f = emb[id];                   // L2-resident table -> hit
    v2f v; v.x = f.x; v.y = f.y;
    __builtin_nontemporal_store(v, ws + (size_t)level * N + i);  // dense 8B store
}

// ---------------- K2: gather-free assemble ----------------
// Streams ws + inputs, recomputes weights (VALU is ~5% busy - free),
// stages the 43-float row in LDS, writes the block tile with nt float4.
__global__ __launch_bounds__(TPB) void assemble_kernel(
    const float* __restrict__ inputs,   // [N,3]
    const v2f* __restrict__ ws,         // [8][N]
    float* __restrict__ out,            // [N,43]
    int N)
{
    __shared__ __align__(16) float lds[TPB * COLS];   // 11008 B
    const int tid = threadIdx.x;
    const int i = blockIdx.x * TPB + tid;

    if (i < N) {
        // issue all 8 streaming feat loads back-to-back (independent)
        v2f f[NLEV];
        #pragma unroll
        for (int L = 0; L < NLEV; ++L)
            f[L] = __builtin_nontemporal_load(ws + (size_t)L * N + i);

        const float x0 = inputs[3 * i + 0];
        const float x1 = inputs[3 * i + 1];
        const float x2 = inputs[3 * i + 2];
        float* row = &lds[tid * COLS];   // stride 43: odd -> 2-way bank alias (free)

        #pragma unroll
        for (int L = 0; L < NLEV; ++L) {
            const float res = (float)(16 << L);
            const float a = x0 * res, b = x1 * res, c = x2 * res;
            const float ga = a - floorf(a), gb = b - floorf(b), gc = c - floorf(c);
            row[5 * L + 2] = ga < 0.5f ? ga : 1.0f - ga;
            row[5 * L + 3] = gb < 0.5f ? gb : 1.0f - gb;
            row[5 * L + 4] = gc < 0.5f ? gc : 1.0f - gc;
        }
        #pragma unroll
        for (int L = 0; L < NLEV; ++L) {
            row[5 * L + 0] = f[L].x;
            row[5 * L + 1] = f[L].y;
        }
        row[40] = x0;
        row[41] = x1;
        row[42] = x2;
    }
    __syncthreads();   // single-wave block: wave-local, just orders LDS

    const long long tile_base = (long long)blockIdx.x * (TPB * COLS);
    if ((blockIdx.x + 1) * TPB <= N) {
        v4f* __restrict__ out4 = (v4f*)(out + tile_base);
        const v4f* l4 = (const v4f*)lds;
        const int NV = TPB * COLS / 4;      // 688
        #pragma unroll
        for (int j = 0; j < 10; ++j) {
            const int k = tid + j * TPB;
            __builtin_nontemporal_store(l4[k], &out4[k]);
        }
        const int k = tid + 10 * TPB;
        if (k < NV)
            __builtin_nontemporal_store(l4[k], &out4[k]);
    } else {
        const int valid = N - blockIdx.x * TPB;
        const int NT = valid * COLS;
        for (int k = tid; k < NT; k += TPB)
            out[tile_base + k] = lds[k];
    }
}

// ---------------- fallback: round-2 single kernel (ws too small) ----------------
__global__ __launch_bounds__(TPB) void hashgrid_kernel(
    const float* __restrict__ inputs,
    const float2* __restrict__ emb,
    float* __restrict__ out,
    int N)
{
    __shared__ __align__(16) float lds[TPB * COLS];
    const int tid = threadIdx.x;
    const int i = blockIdx.x * TPB + tid;

    if (i < N) {
        const float x0 = inputs[3 * i + 0];
        const float x1 = inputs[3 * i + 1];
        const float x2 = inputs[3 * i + 2];

        unsigned id[NLEV];
        float ga[NLEV], gb[NLEV], gc[NLEV];
        bool  ma[NLEV], mb[NLEV], mc[NLEV];
        #pragma unroll
        for (int L = 0; L < NLEV; ++L) {
            const float res = (float)(16 << L);
            const float a = x0 * res, b = x1 * res, c = x2 * res;
            const float fa = floorf(a), fb = floorf(b), fc = floorf(c);
            ga[L] = a - fa; gb[L] = b - fb; gc[L] = c - fc;
            ma[L] = ga[L] < 0.5f; mb[L] = gb[L] < 0.5f; mc[L] = gc[L] < 0.5f;
            const unsigned na = (unsigned)fa + (ma[L] ? 0u : 1u);
            const unsigned nb = (unsigned)fb + (mb[L] ? 0u : 1u);
            const unsigned nc = (unsigned)fc + (mc[L] ? 0u : 1u);
            const unsigned h = na ^ (nb * 2654435761u) ^ (nc * 805459861u);
            id[L] = (h & mask_c[L]) + off_c[L];
        }
        float2 f[NLEV];
        #pragma unroll
        for (int L = 0; L < NLEV; ++L) f[L] = emb[id[L]];

        float* row = &lds[tid * COLS];
        #pragma unroll
        for (int L = 0; L < NLEV; ++L) {
            row[5 * L + 2] = ma[L] ? ga[L] : 1.0f - ga[L];
            row[5 * L + 3] = mb[L] ? gb[L] : 1.0f - gb[L];
            row[5 * L + 4] = mc[L] ? gc[L] : 1.0f - gc[L];
        }
        row[40] = x0;
        row[41] = x1;
        row[42] = x2;
        #pragma unroll
        for (int L = 0; L < NLEV; ++L) {
            row[5 * L + 0] = f[L].x;
            row[5 * L + 1] = f[L].y;
        }
    }
    __syncthreads();

    const long long tile_base = (long long)blockIdx.x * (TPB * COLS);
    if ((blockIdx.x + 1) * TPB <= N) {
        v4f* __restrict__ out4 = (v4f*)(out + tile_base);
        const v4f* l4 = (const v4f*)lds;
        const int NV = TPB * COLS / 4;
        #pragma unroll
        for (int j = 0; j < 10; ++j) {
            const int k = tid + j * TPB;
            __builtin_nontemporal_store(l4[k], &out4[k]);
        }
        const int k = tid + 10 * TPB;
        if (k < NV)
            __builtin_nontemporal_store(l4[k], &out4[k]);
    } else {
        const int valid = N - blockIdx.x * TPB;
        const int NT = valid * COLS;
        for (int k = tid; k < NT; k += TPB)
            out[tile_base + k] = lds[k];
    }
}

extern "C" void kernel_launch(void* const* d_in, const int* in_sizes, int n_in,
                              void* d_out, int out_size, void* d_ws, size_t ws_size,
                              hipStream_t stream) {
    const float*  inputs = (const float*)d_in[0];
    const float2* emb    = (const float2*)d_in[1];
    float* out = (float*)d_out;
    const int N = in_sizes[0] / 3;   // 2097152

    const size_t ws_need = (size_t)NLEV * N * sizeof(float2);  // 134 MB
    if (d_ws != nullptr && ws_size >= ws_need) {
        const int chunks = (N + TPB1 - 1) / TPB1;   // 8192
        gather_kernel<<<chunks * NLEV, TPB1, 0, stream>>>(inputs, emb, (v2f*)d_ws, N);
        const int grid2 = (N + TPB - 1) / TPB;
        assemble_kernel<<<grid2, TPB, 0, stream>>>(inputs, (const v2f*)d_ws, out, N);
    } else {
        const int grid = (N + TPB - 1) / TPB;
        hashgrid_kernel<<<grid, TPB, 0, stream>>>(inputs, emb, out, N);
    }
}